// Round 4
// baseline (248.322 us; speedup 1.0000x reference)
//
#include <hip/hip_runtime.h>

// ROI bilinear pooling (tf.image.resize half-pixel centers), POOL=7.
// img: (1, 64, 64, 1024) fp32 NHWC. rois: (1, R, 4) int32 = [x, y, w, h].
// out: (1, R, 7, 7, 1024) fp32.
//
// R3 structure: one block per (ROI, 64-channel group). Stage the ROI's
// rw x rh source box (channel slice) into LDS with async global_load_lds
// (16B/lane) -- every unique (pixel, slice) byte read from global EXACTLY
// once: 822 MB logical gathers -> 295 MB structural reads, no reliance on
// XCD dispatch policy / L2 luck. Compute 49 cells from LDS, NT-store.
// LDS worst case 16*16 px * 64ch * 4B = 64 KB -> 2 blocks/CU.

#define POOLSZ 7
#define IMG_W 64
#define IMG_C 1024
#define GROUP 64              // channels per block
#define NQUAD (GROUP / 4)     // 16 float4 slots per pixel slice
#define NGROUP (IMG_C / GROUP) // 16 blocks per ROI
#define MAXPX 256             // 16x16 max box

typedef float v4f __attribute__((ext_vector_type(4)));
typedef __attribute__((address_space(1))) const void as1_cvoid;
typedef __attribute__((address_space(3))) void as3_void;

__global__ __launch_bounds__(256, 2) void roi_pool_lds_kernel(
    const float* __restrict__ img,
    const int* __restrict__ rois,
    float* __restrict__ out) {

    __shared__ v4f smem[MAXPX * NQUAD];   // 64 KB

    const int bid = blockIdx.x;
    const int g   = bid & (NGROUP - 1);   // channel group
    const int r   = bid >> 4;             // roi

    const int4 roi = ((const int4*)rois)[r];
    const int rx = roi.x, ry = roi.y, rw = roi.z, rh = roi.w;
    const int npx   = rw * rh;            // <= 256
    const int total = npx * NQUAD;        // float4s to stage, <= 4096

    // exact small-range div-by-rw: p/rw == (p*magic)>>16 for p<=255, rw<=16
    const unsigned magic = (65536u + (unsigned)rw - 1u) / (unsigned)rw;

    const float* src0 = img + ((size_t)ry * IMG_W + rx) * IMG_C + g * GROUP;

    const int tid  = threadIdx.x;
    const int wave = tid >> 6;

    // ---- stage: async global->LDS, 16B per lane, each byte fetched once ----
    const int nfull = total & ~255;
    for (int base = 0; base < nfull; base += 256) {
        const int idx = base + tid;
        const int p   = idx >> 4;          // pixel (row-major in box)
        const int q   = idx & 15;          // float4 within slice
        const int py  = (int)(((unsigned)p * magic) >> 16);
        const int px  = p - py * rw;
        const float* src = src0 + ((size_t)((py << 6) + px)) * IMG_C + (q << 2);
        __builtin_amdgcn_global_load_lds(
            (as1_cvoid*)src,
            (as3_void*)&smem[base + (wave << 6)],  // wave-uniform base; lane*16 dest
            16, 0, 0);
    }
    // tail (partial chunk): plain load + LDS write
    for (int idx = nfull + tid; idx < total; idx += 256) {
        const int p  = idx >> 4;
        const int q  = idx & 15;
        const int py = (int)(((unsigned)p * magic) >> 16);
        const int px = p - py * rw;
        smem[idx] = ((const v4f*)(src0 + ((size_t)((py << 6) + px)) * IMG_C))[q];
    }
    __builtin_amdgcn_s_waitcnt(0);   // drain global_load_lds before LDS reads
    __syncthreads();

    // ---- compute: 49 cells x 16 quads from LDS ----
    const int q    = tid & 15;   // float4 within slice
    const int slot = tid >> 4;   // 16 cell slots

    const float inv7 = 1.0f / 7.0f;
    const float scx  = (float)rw * inv7;
    const float scy  = (float)rh * inv7;

    v4f* out4 = (v4f*)out + (size_t)r * (POOLSZ * POOLSZ) * (IMG_C / 4)
                + g * NQUAD + q;

#pragma unroll
    for (int it = 0; it < 4; ++it) {
        const int cell = it * 16 + slot;
        if (cell < POOLSZ * POOLSZ) {
            const int cy = cell / POOLSZ;        // compile-time magic div
            const int cx = cell - cy * POOLSZ;

            // src = (p+0.5)*size/7 - 0.5; lerp from unclipped floor (ref semantics)
            const float srcy = ((float)cy + 0.5f) * scy - 0.5f;
            const float fy   = floorf(srcy);
            const float ty   = srcy - fy;
            const int   iy   = (int)fy;
            const int   y0   = min(max(iy,     0), rh - 1);
            const int   y1   = min(max(iy + 1, 0), rh - 1);

            const float srcx = ((float)cx + 0.5f) * scx - 0.5f;
            const float fx   = floorf(srcx);
            const float tx   = srcx - fx;
            const int   ix   = (int)fx;
            const int   x0   = min(max(ix,     0), rw - 1);
            const int   x1   = min(max(ix + 1, 0), rw - 1);

            const v4f a = smem[(y0 * rw + x0) * NQUAD + q];
            const v4f b = smem[(y0 * rw + x1) * NQUAD + q];
            const v4f c = smem[(y1 * rw + x0) * NQUAD + q];
            const v4f d = smem[(y1 * rw + x1) * NQUAD + q];

            const v4f top = a + (b - a) * tx;
            const v4f bot = c + (d - c) * tx;
            const v4f o   = top + (bot - top) * ty;
            __builtin_nontemporal_store(o, out4 + (size_t)cell * (IMG_C / 4));
        }
    }
}

extern "C" void kernel_launch(void* const* d_in, const int* in_sizes, int n_in,
                              void* d_out, int out_size, void* d_ws, size_t ws_size,
                              hipStream_t stream) {
    const float* img  = (const float*)d_in[0];
    const int*   rois = (const int*)d_in[1];
    float*       out  = (float*)d_out;
    const int R = in_sizes[1] / 4;            // rois: (1, R, 4)
    const int n_blocks = R * NGROUP;          // 1024*16 = 16384
    roi_pool_lds_kernel<<<n_blocks, 256, 0, stream>>>(img, rois, out);
}

// Round 5
// 235.597 us; speedup vs baseline: 1.0540x; 1.0540x over previous
//
#include <hip/hip_runtime.h>

// ROI bilinear pooling (tf.image.resize half-pixel centers), POOL=7.
// img: (1, 64, 64, 1024) fp32, NHWC. rois: (1, R, 4) int32 = [x, y, w, h].
// out: (1, R, 7, 7, 1024) fp32.
//
// R4 = R2 row kernel with ONE change: plain stores instead of nontemporal.
// A/B on the nt bit: the harness poison-fills hit 6.5 TB/s with plain
// stores; all NT variants of this kernel sit ~2 TB/s effective on the
// 205 MB output. R3 proved the read path is irrelevant (structural dedup
// regressed), so the write path is the remaining suspect.
//
// One block per (roi, py) row: 7 output cells. 256 threads, each owns a
// float4 channel slice, issues all 28 bilinear taps up-front, blends,
// stores 7 outputs (each wave store = 1 KB contiguous).

#define POOLSZ 7
#define IMG_H 64
#define IMG_W 64
#define IMG_C 1024
#define NUM_XCD 8

typedef float v4f __attribute__((ext_vector_type(4)));

__global__ __launch_bounds__(256, 1) void roi_pool_row_kernel(
    const float* __restrict__ img,
    const int* __restrict__ rois,
    float* __restrict__ out,
    int roisPerXcd) {            // R/8 when R%8==0, else 0 (identity mapping)
    int r, py;
    if (roisPerXcd > 0) {
        // xcd = blockIdx % 8; chunk ROIs per XCD for L2 locality.
        const int xcd   = blockIdx.x & (NUM_XCD - 1);
        const int local = blockIdx.x >> 3;           // 0 .. R/8*7-1
        r  = xcd * roisPerXcd + local / POOLSZ;
        py = local % POOLSZ;
    } else {
        r  = blockIdx.x / POOLSZ;
        py = blockIdx.x % POOLSZ;
    }

    const int4 roi = ((const int4*)rois)[r];
    const int rx = roi.x, ry = roi.y, rw = roi.z, rh = roi.w;

    // y coords: src = (py+0.5)*h/7 - 0.5; lerp from unclipped floor (ref semantics)
    const float scy  = (float)rh * (1.0f / (float)POOLSZ);
    const float srcy = ((float)py + 0.5f) * scy - 0.5f;
    const float fy   = floorf(srcy);
    const float ty   = srcy - fy;
    const int   iy   = (int)fy;
    const int   y0   = ry + min(max(iy,     0), rh - 1);
    const int   y1   = ry + min(max(iy + 1, 0), rh - 1);

    // x coords for all 7 cells
    int   x0[POOLSZ], x1[POOLSZ];
    float tx[POOLSZ];
    const float scx = (float)rw * (1.0f / (float)POOLSZ);
#pragma unroll
    for (int px = 0; px < POOLSZ; ++px) {
        const float srcx = ((float)px + 0.5f) * scx - 0.5f;
        const float fx   = floorf(srcx);
        tx[px] = srcx - fx;
        const int ix = (int)fx;
        x0[px] = rx + min(max(ix,     0), rw - 1);
        x1[px] = rx + min(max(ix + 1, 0), rw - 1);
    }

    const int c4 = threadIdx.x;  // 0..255: float4 channel slice
    const v4f* row0 = (const v4f*)(img + (size_t)y0 * IMG_W * IMG_C) + c4;
    const v4f* row1 = (const v4f*)(img + (size_t)y1 * IMG_W * IMG_C) + c4;

    // Issue all 28 loads before any arithmetic (deep MLP).
    v4f a[POOLSZ], b[POOLSZ], c[POOLSZ], d[POOLSZ];
#pragma unroll
    for (int px = 0; px < POOLSZ; ++px) {
        a[px] = row0[(size_t)x0[px] * (IMG_C / 4)];
        b[px] = row0[(size_t)x1[px] * (IMG_C / 4)];
        c[px] = row1[(size_t)x0[px] * (IMG_C / 4)];
        d[px] = row1[(size_t)x1[px] * (IMG_C / 4)];
    }

    // out = (a*(1-tx)+b*tx)*(1-ty) + (c*(1-tx)+d*tx)*ty
    v4f* dst = (v4f*)out + ((size_t)r * POOLSZ + py) * POOLSZ * (IMG_C / 4) + c4;
#pragma unroll
    for (int px = 0; px < POOLSZ; ++px) {
        const v4f top = a[px] + (b[px] - a[px]) * tx[px];
        const v4f bot = c[px] + (d[px] - c[px]) * tx[px];
        const v4f o   = top + (bot - top) * ty;
        dst[(size_t)px * (IMG_C / 4)] = o;   // plain store (A/B vs NT)
    }
}

extern "C" void kernel_launch(void* const* d_in, const int* in_sizes, int n_in,
                              void* d_out, int out_size, void* d_ws, size_t ws_size,
                              hipStream_t stream) {
    const float* img  = (const float*)d_in[0];
    const int*   rois = (const int*)d_in[1];
    float*       out  = (float*)d_out;
    const int R = in_sizes[1] / 4;                  // rois: (1, R, 4)
    const int n_rows = R * POOLSZ;                  // 1024*7 = 7168 blocks
    const int roisPerXcd = (R % NUM_XCD == 0) ? (R / NUM_XCD) : 0;
    roi_pool_row_kernel<<<n_rows, 256, 0, stream>>>(img, rois, out, roisPerXcd);
}